// Round 9
// baseline (288.953 us; speedup 1.0000x reference)
//
#include <hip/hip_runtime.h>
#include <math.h>

#define H 2048
#define E 64
#define MR 8         // rows per block (MFMA m-tile padded with a zero row)
#define NCH 16       // 128-wide k chunks
#define LR 136       // LDS row stride in f16 (128 + 8 pad; 272 B rows, 16B-aligned)

typedef _Float16 half8  __attribute__((ext_vector_type(8)));
typedef _Float16 half4h __attribute__((ext_vector_type(4)));
typedef float    f32x4  __attribute__((ext_vector_type(4)));

#define MFMA16(A,B,C) __builtin_amdgcn_mfma_f32_16x16x32_f16(A,B,C,0,0,0)

// ws layout: Bh[H*E f16] | Bl[H*E f16] | csum[E f32] | bsum[E f32]

// Fused prep: pack W' = lnw*W into MFMA B-fragment layout (hi/lo f16 planes,
// lo scaled by 2048)  +  per-expert csum/bsum reductions. Grid = 64.
// Verified numerics-neutral in R6/R7/R8.
__global__ __launch_bounds__(256) void prep_fused(const float* __restrict__ W,
        const float* __restrict__ lnw, const float* __restrict__ lnb,
        _Float16* __restrict__ Bh, _Float16* __restrict__ Bl,
        float* __restrict__ csum, float* __restrict__ bsum) {
    // ---- pack part ----
    {
        int idx  = blockIdx.x * 256 + threadIdx.x;      // 0..16383
        int lane = idx & 63;
        int e  = ((idx >> 6) & 3) * 16 + (lane & 15);
        int k0 = (idx >> 8) * 32 + ((lane >> 4) << 3);
        half8 hh, ll;
        #pragma unroll
        for (int j = 0; j < 8; ++j) {
            float wf = lnw[k0 + j] * W[e * H + k0 + j];
            _Float16 h = (_Float16)wf;
            _Float16 l = (_Float16)((wf - (float)h) * 2048.0f);
            hh[j] = h; ll[j] = l;
        }
        *(half8*)&Bh[(long)idx * 8] = hh;
        *(half8*)&Bl[(long)idx * 8] = ll;
    }
    // ---- sums part (expert = blockIdx.x) ----
    {
        __shared__ float rc[256], rb[256];
        int e = blockIdx.x, t = threadIdx.x;
        float cs = 0.f, bs = 0.f;
        #pragma unroll
        for (int j = 0; j < 8; ++j) {
            int k = t + j * 256;
            float w = W[e * H + k];
            cs += lnw[k] * w;
            bs += lnb[k] * w;
        }
        rc[t] = cs; rb[t] = bs;
        __syncthreads();
        for (int s = 128; s > 0; s >>= 1) {
            if (t < s) { rc[t] += rc[t + s]; rb[t] += rb[t + s]; }
            __syncthreads();
        }
        if (t == 0) { csum[e] = rc[0]; bsum[e] = rb[0]; }
    }
}

// MR=8 router: same verified dataflow and per-row MFMA order as R3/R8, but
// 2048 blocks (8/CU available, 6 resident at launch_bounds(256,6)) to lift
// the grid-limited occupancy. MFMA m-tile rows 8-15 map to one shared zero
// row (broadcast LDS read, exact-zero products). X prefetch 2 chunks deep
// (1 float4/thread/chunk now), W loads iteration-scoped (promotable, R7/R8).
__global__ __launch_bounds__(256, 6) void router_kernel(
    const float* __restrict__ X, const _Float16* __restrict__ Bh,
    const _Float16* __restrict__ Bl, const float* __restrict__ csum,
    const float* __restrict__ bsum, float* __restrict__ out, int nRows)
{
    __shared__ __align__(16) _Float16 Xh[2][MR + 1][LR];   // 4,896 B (row 8 = zeros)
    __shared__ __align__(16) _Float16 Xl[2][MR + 1][LR];   // 4,896 B
    __shared__ float C2[MR][E + 4];                        // 2,176 B
    __shared__ float mu_s[MR], rs_s[MR];
    // ~12.0 KB LDS -> 6 blocks/CU resident (launch_bounds), 8 available

    const int t    = threadIdx.x;
    const int lane = t & 63;
    const int et   = t >> 6;                 // wave -> expert tile (16 experts)
    const int q    = lane >> 4;
    const int ln16 = lane & 15;
    const int arow = (ln16 < MR) ? ln16 : MR;  // A row; pads -> zero row (const/thread)
    const int rowR = t >> 5;                 // staging/stats row 0..7 (32 thr/row)
    const int cS   = t & 31;                 // float4 col within chunk
    const long rowBase = (long)blockIdx.x * MR;
    const long iOff = (long)nRows * 2;
    const long lOff = (long)nRows * 4;

    const float4* Xrow = (const float4*)X + (rowBase + rowR) * 512;

    // zero-row init (rows never rewritten; convert only touches rows 0..7)
    if (t < LR) {
        Xh[0][MR][t] = (_Float16)0.f; Xh[1][MR][t] = (_Float16)0.f;
        Xl[0][MR][t] = (_Float16)0.f; Xl[1][MR][t] = (_Float16)0.f;
    }

    float sacc = 0.f, qacc = 0.f;            // LN stats, fixed row per thread
    f32x4 acc0 = (f32x4)0.f;
    f32x4 acc1 = (f32x4)0.f;

    // convert one float4 (by value) into buf; hi/lo split, stats first
    auto convert = [&](float4 v, int buf) {
        sacc += v.x + v.y + v.z + v.w;
        qacc += v.x * v.x + v.y * v.y + v.z * v.z + v.w * v.w;
        _Float16 h0 = (_Float16)v.x, h1 = (_Float16)v.y,
                 h2 = (_Float16)v.z, h3 = (_Float16)v.w;
        _Float16 l0 = (_Float16)((v.x - (float)h0) * 2048.f);
        _Float16 l1 = (_Float16)((v.y - (float)h1) * 2048.f);
        _Float16 l2 = (_Float16)((v.z - (float)h2) * 2048.f);
        _Float16 l3 = (_Float16)((v.w - (float)h3) * 2048.f);
        half4h hh = {h0, h1, h2, h3};
        half4h ll = {l0, l1, l2, l3};
        *(half4h*)&Xh[buf][rowR][cS * 4] = hh;
        *(half4h*)&Xl[buf][rowR][cS * 4] = ll;
    };
    // iteration-scoped W load + MFMA for one chunk (verbatim R3/R8 order)
    auto loadW = [&](half8* Wh, half8* Wl, int c) {
        #pragma unroll
        for (int ks = 0; ks < 4; ++ks) {
            int bo = (((c * 4 + ks) * 4 + et) * 64 + lane) * 8;
            Wh[ks] = *(const half8*)&Bh[bo];
            Wl[ks] = *(const half8*)&Bl[bo];
        }
    };
    auto mfmaC = [&](const half8* Wh, const half8* Wl, int buf) {
        #pragma unroll
        for (int ks = 0; ks < 4; ++ks) {
            half8 Ah = *(const half8*)&Xh[buf][arow][ks * 32 + q * 8];
            half8 Al = *(const half8*)&Xl[buf][arow][ks * 32 + q * 8];
            acc0 = MFMA16(Ah, Wh[ks], acc0);
            acc1 = MFMA16(Ah, Wl[ks], acc1);
            acc1 = MFMA16(Al, Wh[ks], acc1);
        }
    };

    // loop-carried X prefetch: 2 chunks deep, one named float4 each
    float4 vA0, vB0;

    // prologue: X(0) load+convert into buf0, X(1) -> vA0
    {
        float4 v00 = Xrow[cS];
        vA0 = Xrow[32 + cS];
        convert(v00, 0);
    }
    __syncthreads();

    for (int c = 0; c < NCH; c += 2) {
        // ---- even chunk c: MFMA buf0; vA holds X(c+1); issue X(c+2)->vB ----
        {
            half8 Wh[4], Wl[4];
            loadW(Wh, Wl, c);
            if (c + 2 < NCH) vB0 = Xrow[(c + 2) * 32 + cS];
            mfmaC(Wh, Wl, 0);
            convert(vA0, 1);
        }
        __syncthreads();

        // ---- odd chunk c+1: MFMA buf1; vB holds X(c+2); issue X(c+3)->vA ----
        {
            half8 Wh[4], Wl[4];
            loadW(Wh, Wl, c + 1);
            if (c + 3 < NCH) vA0 = Xrow[(c + 3) * 32 + cS];
            mfmaC(Wh, Wl, 1);
            if (c + 2 < NCH) convert(vB0, 0);
        }
        __syncthreads();
    }

    // ---- finalize LN stats (32 lanes per row: bits 0-4 of lane) ----
    {
        float s = sacc, qq = qacc;
        #pragma unroll
        for (int d = 1; d < 32; d <<= 1) {
            s  += __shfl_xor(s, d);
            qq += __shfl_xor(qq, d);
        }
        if (cS == 0) {
            float mu  = s * (1.f / H);
            float var = qq * (1.f / H) - mu * mu;
            mu_s[rowR] = mu;
            rs_s[rowR] = rsqrtf(var + 1e-5f);
        }
    }
    __syncthreads();

    // ---- epilogue: combine splits, LN rank-1 correction, clip, write logits ----
    if (q < 2) {
        int n = et * 16 + ln16;
        float cs = csum[n], bs = bsum[n];
        #pragma unroll
        for (int reg = 0; reg < 4; ++reg) {
            int r = q * 4 + reg;                       // 0..7
            float raw = acc0[reg] + acc1[reg] * (1.f / 2048.f);
            float lg = rs_s[r] * (raw - mu_s[r] * cs) + bs;
            lg = fminf(fmaxf(lg, -10.f), 10.f);
            out[lOff + (rowBase + r) * 64 + n] = lg;
            C2[r][n] = lg;
        }
    }
    __syncthreads();

    // ---- softmax + top2: wave et handles rows et*2, et*2+1 ----
    #pragma unroll
    for (int rr = 0; rr < 2; ++rr) {
        int r = et * 2 + rr;
        float l = C2[r][lane];
        float m = l;
        #pragma unroll
        for (int d = 1; d < 64; d <<= 1) m = fmaxf(m, __shfl_xor(m, d));
        float p = __expf(l - m);
        float ssum = p;
        #pragma unroll
        for (int d = 1; d < 64; d <<= 1) ssum += __shfl_xor(ssum, d);
        float prob = fminf(fmaxf(p / ssum, 1e-4f), 1.0f);

        float v1 = prob; int i1 = lane;
        #pragma unroll
        for (int d = 1; d < 64; d <<= 1) {
            float ov = __shfl_xor(v1, d);
            int   oi = __shfl_xor(i1, d);
            if (ov > v1 || (ov == v1 && oi < i1)) { v1 = ov; i1 = oi; }
        }
        float v2 = (lane == i1) ? -1.f : prob; int i2 = lane;
        #pragma unroll
        for (int d = 1; d < 64; d <<= 1) {
            float ov = __shfl_xor(v2, d);
            int   oi = __shfl_xor(i2, d);
            if (ov > v2 || (ov == v2 && oi < i2)) { v2 = ov; i2 = oi; }
        }
        if (lane == 0) {
            float ps = fmaxf(v1 + v2, 1e-4f);
            long rg_ = rowBase + r;
            out[rg_ * 2 + 0] = v1 / ps;
            out[rg_ * 2 + 1] = v2 / ps;
            out[iOff + rg_ * 2 + 0] = (float)i1;
            out[iOff + rg_ * 2 + 1] = (float)i2;
        }
    }
}

extern "C" void kernel_launch(void* const* d_in, const int* in_sizes, int n_in,
                              void* d_out, int out_size, void* d_ws, size_t ws_size,
                              hipStream_t stream) {
    const float* X   = (const float*)d_in[0];
    const float* lnw = (const float*)d_in[1];
    const float* lnb = (const float*)d_in[2];
    const float* W   = (const float*)d_in[3];
    float* outp = (float*)d_out;

    _Float16* Bh = (_Float16*)d_ws;
    _Float16* Bl = Bh + H * E;
    float* csum  = (float*)(Bl + H * E);
    float* bsum  = csum + E;

    int N = in_sizes[0] / H;                 // 16384 rows

    prep_fused<<<64, 256, 0, stream>>>(W, lnw, lnb, Bh, Bl, csum, bsum);
    router_kernel<<<N / MR, 256, 0, stream>>>(X, Bh, Bl, csum, bsum, outp, N);
}

// Round 10
// 234.388 us; speedup vs baseline: 1.2328x; 1.2328x over previous
//
#include <hip/hip_runtime.h>
#include <math.h>

#define H 2048
#define E 64
#define MR 8         // rows per block (MFMA m-tile padded with a zero row)
#define NCH 16       // 128-wide k chunks
#define LR 136       // LDS row stride in f16 (128 + 8 pad; 272 B rows, 16B-aligned)

typedef _Float16 half8  __attribute__((ext_vector_type(8)));
typedef _Float16 half4h __attribute__((ext_vector_type(4)));
typedef float    f32x4  __attribute__((ext_vector_type(4)));

#define MFMA16(A,B,C) __builtin_amdgcn_mfma_f32_16x16x32_f16(A,B,C,0,0,0)

// ws layout: Bh[H*E f16] | Bl[H*E f16] | csum[E f32] | bsum[E f32]

// Fused prep: pack W' = lnw*W into MFMA B-fragment layout (hi/lo f16 planes,
// lo scaled by 2048)  +  per-expert csum/bsum reductions. Grid = 64.
// Verified numerics-neutral in R6-R9.
__global__ __launch_bounds__(256) void prep_fused(const float* __restrict__ W,
        const float* __restrict__ lnw, const float* __restrict__ lnb,
        _Float16* __restrict__ Bh, _Float16* __restrict__ Bl,
        float* __restrict__ csum, float* __restrict__ bsum) {
    // ---- pack part ----
    {
        int idx  = blockIdx.x * 256 + threadIdx.x;      // 0..16383
        int lane = idx & 63;
        int e  = ((idx >> 6) & 3) * 16 + (lane & 15);
        int k0 = (idx >> 8) * 32 + ((lane >> 4) << 3);
        half8 hh, ll;
        #pragma unroll
        for (int j = 0; j < 8; ++j) {
            float wf = lnw[k0 + j] * W[e * H + k0 + j];
            _Float16 h = (_Float16)wf;
            _Float16 l = (_Float16)((wf - (float)h) * 2048.0f);
            hh[j] = h; ll[j] = l;
        }
        *(half8*)&Bh[(long)idx * 8] = hh;
        *(half8*)&Bl[(long)idx * 8] = ll;
    }
    // ---- sums part (expert = blockIdx.x) ----
    {
        __shared__ float rc[256], rb[256];
        int e = blockIdx.x, t = threadIdx.x;
        float cs = 0.f, bs = 0.f;
        #pragma unroll
        for (int j = 0; j < 8; ++j) {
            int k = t + j * 256;
            float w = W[e * H + k];
            cs += lnw[k] * w;
            bs += lnb[k] * w;
        }
        rc[t] = cs; rb[t] = bs;
        __syncthreads();
        for (int s = 128; s > 0; s >>= 1) {
            if (t < s) { rc[t] += rc[t + s]; rb[t] += rb[t + s]; }
            __syncthreads();
        }
        if (t == 0) { csum[e] = rc[0]; bsum[e] = rb[0]; }
    }
}

// MR=8 router, grid 2048 (8 blocks/CU available). IDENTICAL to R9 except
// __launch_bounds__(256,4): R9's (256,6) capped VGPRs at ~85 and spilled the
// iteration-scoped W sets to scratch (VGPR 40, WRITE_SIZE 53 MB). At cap 128
// the same code held W in registers in R8 (VGPR 64) -> HW can still schedule
// 8 waves/SIMD, so residency comes from resources, not the bound.
__global__ __launch_bounds__(256, 4) void router_kernel(
    const float* __restrict__ X, const _Float16* __restrict__ Bh,
    const _Float16* __restrict__ Bl, const float* __restrict__ csum,
    const float* __restrict__ bsum, float* __restrict__ out, int nRows)
{
    __shared__ __align__(16) _Float16 Xh[2][MR + 1][LR];   // 4,896 B (row 8 = zeros)
    __shared__ __align__(16) _Float16 Xl[2][MR + 1][LR];   // 4,896 B
    __shared__ float C2[MR][E + 4];                        // 2,176 B
    __shared__ float mu_s[MR], rs_s[MR];
    // ~12.0 KB LDS -> 13 blocks/CU LDS-capacity; grid supplies 8

    const int t    = threadIdx.x;
    const int lane = t & 63;
    const int et   = t >> 6;                 // wave -> expert tile (16 experts)
    const int q    = lane >> 4;
    const int ln16 = lane & 15;
    const int arow = (ln16 < MR) ? ln16 : MR;  // A row; pads -> zero row (const/thread)
    const int rowR = t >> 5;                 // staging/stats row 0..7 (32 thr/row)
    const int cS   = t & 31;                 // float4 col within chunk
    const long rowBase = (long)blockIdx.x * MR;
    const long iOff = (long)nRows * 2;
    const long lOff = (long)nRows * 4;

    const float4* Xrow = (const float4*)X + (rowBase + rowR) * 512;

    // zero-row init (rows never rewritten; convert only touches rows 0..7)
    if (t < LR) {
        Xh[0][MR][t] = (_Float16)0.f; Xh[1][MR][t] = (_Float16)0.f;
        Xl[0][MR][t] = (_Float16)0.f; Xl[1][MR][t] = (_Float16)0.f;
    }

    float sacc = 0.f, qacc = 0.f;            // LN stats, fixed row per thread
    f32x4 acc0 = (f32x4)0.f;
    f32x4 acc1 = (f32x4)0.f;

    // convert one float4 (by value) into buf; hi/lo split, stats first
    auto convert = [&](float4 v, int buf) {
        sacc += v.x + v.y + v.z + v.w;
        qacc += v.x * v.x + v.y * v.y + v.z * v.z + v.w * v.w;
        _Float16 h0 = (_Float16)v.x, h1 = (_Float16)v.y,
                 h2 = (_Float16)v.z, h3 = (_Float16)v.w;
        _Float16 l0 = (_Float16)((v.x - (float)h0) * 2048.f);
        _Float16 l1 = (_Float16)((v.y - (float)h1) * 2048.f);
        _Float16 l2 = (_Float16)((v.z - (float)h2) * 2048.f);
        _Float16 l3 = (_Float16)((v.w - (float)h3) * 2048.f);
        half4h hh = {h0, h1, h2, h3};
        half4h ll = {l0, l1, l2, l3};
        *(half4h*)&Xh[buf][rowR][cS * 4] = hh;
        *(half4h*)&Xl[buf][rowR][cS * 4] = ll;
    };
    // iteration-scoped W load + MFMA for one chunk (verbatim R3/R8 order)
    auto loadW = [&](half8* Wh, half8* Wl, int c) {
        #pragma unroll
        for (int ks = 0; ks < 4; ++ks) {
            int bo = (((c * 4 + ks) * 4 + et) * 64 + lane) * 8;
            Wh[ks] = *(const half8*)&Bh[bo];
            Wl[ks] = *(const half8*)&Bl[bo];
        }
    };
    auto mfmaC = [&](const half8* Wh, const half8* Wl, int buf) {
        #pragma unroll
        for (int ks = 0; ks < 4; ++ks) {
            half8 Ah = *(const half8*)&Xh[buf][arow][ks * 32 + q * 8];
            half8 Al = *(const half8*)&Xl[buf][arow][ks * 32 + q * 8];
            acc0 = MFMA16(Ah, Wh[ks], acc0);
            acc1 = MFMA16(Ah, Wl[ks], acc1);
            acc1 = MFMA16(Al, Wh[ks], acc1);
        }
    };

    // loop-carried X prefetch: 2 chunks deep, one named float4 each
    float4 vA0, vB0;

    // prologue: X(0) load+convert into buf0, X(1) -> vA0
    {
        float4 v00 = Xrow[cS];
        vA0 = Xrow[32 + cS];
        convert(v00, 0);
    }
    __syncthreads();

    for (int c = 0; c < NCH; c += 2) {
        // ---- even chunk c: MFMA buf0; vA holds X(c+1); issue X(c+2)->vB ----
        {
            half8 Wh[4], Wl[4];
            loadW(Wh, Wl, c);
            if (c + 2 < NCH) vB0 = Xrow[(c + 2) * 32 + cS];
            mfmaC(Wh, Wl, 0);
            convert(vA0, 1);
        }
        __syncthreads();

        // ---- odd chunk c+1: MFMA buf1; vB holds X(c+2); issue X(c+3)->vA ----
        {
            half8 Wh[4], Wl[4];
            loadW(Wh, Wl, c + 1);
            if (c + 3 < NCH) vA0 = Xrow[(c + 3) * 32 + cS];
            mfmaC(Wh, Wl, 1);
            if (c + 2 < NCH) convert(vB0, 0);
        }
        __syncthreads();
    }

    // ---- finalize LN stats (32 lanes per row: bits 0-4 of lane) ----
    {
        float s = sacc, qq = qacc;
        #pragma unroll
        for (int d = 1; d < 32; d <<= 1) {
            s  += __shfl_xor(s, d);
            qq += __shfl_xor(qq, d);
        }
        if (cS == 0) {
            float mu  = s * (1.f / H);
            float var = qq * (1.f / H) - mu * mu;
            mu_s[rowR] = mu;
            rs_s[rowR] = rsqrtf(var + 1e-5f);
        }
    }
    __syncthreads();

    // ---- epilogue: combine splits, LN rank-1 correction, clip, write logits ----
    if (q < 2) {
        int n = et * 16 + ln16;
        float cs = csum[n], bs = bsum[n];
        #pragma unroll
        for (int reg = 0; reg < 4; ++reg) {
            int r = q * 4 + reg;                       // 0..7
            float raw = acc0[reg] + acc1[reg] * (1.f / 2048.f);
            float lg = rs_s[r] * (raw - mu_s[r] * cs) + bs;
            lg = fminf(fmaxf(lg, -10.f), 10.f);
            out[lOff + (rowBase + r) * 64 + n] = lg;
            C2[r][n] = lg;
        }
    }
    __syncthreads();

    // ---- softmax + top2: wave et handles rows et*2, et*2+1 ----
    #pragma unroll
    for (int rr = 0; rr < 2; ++rr) {
        int r = et * 2 + rr;
        float l = C2[r][lane];
        float m = l;
        #pragma unroll
        for (int d = 1; d < 64; d <<= 1) m = fmaxf(m, __shfl_xor(m, d));
        float p = __expf(l - m);
        float ssum = p;
        #pragma unroll
        for (int d = 1; d < 64; d <<= 1) ssum += __shfl_xor(ssum, d);
        float prob = fminf(fmaxf(p / ssum, 1e-4f), 1.0f);

        float v1 = prob; int i1 = lane;
        #pragma unroll
        for (int d = 1; d < 64; d <<= 1) {
            float ov = __shfl_xor(v1, d);
            int   oi = __shfl_xor(i1, d);
            if (ov > v1 || (ov == v1 && oi < i1)) { v1 = ov; i1 = oi; }
        }
        float v2 = (lane == i1) ? -1.f : prob; int i2 = lane;
        #pragma unroll
        for (int d = 1; d < 64; d <<= 1) {
            float ov = __shfl_xor(v2, d);
            int   oi = __shfl_xor(i2, d);
            if (ov > v2 || (ov == v2 && oi < i2)) { v2 = ov; i2 = oi; }
        }
        if (lane == 0) {
            float ps = fmaxf(v1 + v2, 1e-4f);
            long rg_ = rowBase + r;
            out[rg_ * 2 + 0] = v1 / ps;
            out[rg_ * 2 + 1] = v2 / ps;
            out[iOff + rg_ * 2 + 0] = (float)i1;
            out[iOff + rg_ * 2 + 1] = (float)i2;
        }
    }
}

extern "C" void kernel_launch(void* const* d_in, const int* in_sizes, int n_in,
                              void* d_out, int out_size, void* d_ws, size_t ws_size,
                              hipStream_t stream) {
    const float* X   = (const float*)d_in[0];
    const float* lnw = (const float*)d_in[1];
    const float* lnb = (const float*)d_in[2];
    const float* W   = (const float*)d_in[3];
    float* outp = (float*)d_out;

    _Float16* Bh = (_Float16*)d_ws;
    _Float16* Bl = Bh + H * E;
    float* csum  = (float*)(Bl + H * E);
    float* bsum  = csum + E;

    int N = in_sizes[0] / H;                 // 16384 rows

    prep_fused<<<64, 256, 0, stream>>>(W, lnw, lnb, Bh, Bl, csum, bsum);
    router_kernel<<<N / MR, 256, 0, stream>>>(X, Bh, Bl, csum, bsum, outp, N);
}

// Round 11
// 219.021 us; speedup vs baseline: 1.3193x; 1.0702x over previous
//
#include <hip/hip_runtime.h>
#include <math.h>

#define H 2048
#define E 64
#define MR 32        // rows per block: 2 m-tiles x 4 expert-tiles = 8 waves
#define NCH 16       // 128-wide k chunks
#define LR 136       // LDS row stride in f16 (128 + 8 pad; 272 B rows, 16B-aligned)

typedef _Float16 half8  __attribute__((ext_vector_type(8)));
typedef _Float16 half4h __attribute__((ext_vector_type(4)));
typedef float    f32x4  __attribute__((ext_vector_type(4)));

#define MFMA16(A,B,C) __builtin_amdgcn_mfma_f32_16x16x32_f16(A,B,C,0,0,0)

// ws layout: Bh[H*E f16] | Bl[H*E f16] | csum[E f32] | bsum[E f32]

// Fused prep: pack W' = lnw*W into MFMA B-fragment layout (hi/lo f16 planes,
// lo scaled by 2048)  +  per-expert csum/bsum reductions. Grid = 64.
// Verified numerics-neutral in R6-R10.
__global__ __launch_bounds__(256) void prep_fused(const float* __restrict__ W,
        const float* __restrict__ lnw, const float* __restrict__ lnb,
        _Float16* __restrict__ Bh, _Float16* __restrict__ Bl,
        float* __restrict__ csum, float* __restrict__ bsum) {
    // ---- pack part ----
    {
        int idx  = blockIdx.x * 256 + threadIdx.x;      // 0..16383
        int lane = idx & 63;
        int e  = ((idx >> 6) & 3) * 16 + (lane & 15);
        int k0 = (idx >> 8) * 32 + ((lane >> 4) << 3);
        half8 hh, ll;
        #pragma unroll
        for (int j = 0; j < 8; ++j) {
            float wf = lnw[k0 + j] * W[e * H + k0 + j];
            _Float16 h = (_Float16)wf;
            _Float16 l = (_Float16)((wf - (float)h) * 2048.0f);
            hh[j] = h; ll[j] = l;
        }
        *(half8*)&Bh[(long)idx * 8] = hh;
        *(half8*)&Bl[(long)idx * 8] = ll;
    }
    // ---- sums part (expert = blockIdx.x) ----
    {
        __shared__ float rc[256], rb[256];
        int e = blockIdx.x, t = threadIdx.x;
        float cs = 0.f, bs = 0.f;
        #pragma unroll
        for (int j = 0; j < 8; ++j) {
            int k = t + j * 256;
            float w = W[e * H + k];
            cs += lnw[k] * w;
            bs += lnb[k] * w;
        }
        rc[t] = cs; rb[t] = bs;
        __syncthreads();
        for (int s = 128; s > 0; s >>= 1) {
            if (t < s) { rc[t] += rc[t + s]; rb[t] += rb[t + s]; }
            __syncthreads();
        }
        if (t == 0) { csum[e] = rc[0]; bsum[e] = rb[0]; }
    }
}

// MR=32 / 512-thread router: 8 waves = (m-tile mt in {0,1}) x (expert-tile
// et in {0..3}). Per-row compute is BIT-IDENTICAL to R8 (same thread-level
// chunk-sequential 3-MFMA order, same 16-thread/row staging + stats); rows
// 16-31 move from the neighboring R8 block into the mt=1 waves. Halves the
// per-dispatch W L2 traffic (512 blocks x 512 KB) and mt-twin waves share
// W through L1. Grid 512 = 2 blocks/CU x 8 waves = same 16 waves/CU as R8.
__global__ __launch_bounds__(512, 4) void router_kernel(
    const float* __restrict__ X, const _Float16* __restrict__ Bh,
    const _Float16* __restrict__ Bl, const float* __restrict__ csum,
    const float* __restrict__ bsum, float* __restrict__ out, int nRows)
{
    __shared__ __align__(16) _Float16 Xh[2][MR][LR];   // 17,408 B
    __shared__ __align__(16) _Float16 Xl[2][MR][LR];   // 17,408 B
    __shared__ float C2[MR][E + 4];                    //  8,704 B
    __shared__ float mu_s[MR], rs_s[MR];
    // ~44 KB LDS -> 3 blocks/CU capacity; grid supplies 2 (16 waves/CU)

    const int t    = threadIdx.x;                // 0..511
    const int lane = t & 63;
    const int w    = t >> 6;                     // wave 0..7
    const int et   = w & 3;                      // expert tile
    const int mt   = w >> 2;                     // m tile (row half)
    const int q    = lane >> 4;
    const int ln16 = lane & 15;
    const int arow = mt * 16 + ln16;             // A-fragment row (const/thread)
    const int rowR = t >> 4;                     // staging/stats row 0..31 (16 thr/row)
    const int cS   = t & 15;                     // float4 col group within chunk
    const long rowBase = (long)blockIdx.x * MR;
    const long iOff = (long)nRows * 2;
    const long lOff = (long)nRows * 4;

    const float4* Xrow = (const float4*)X + (rowBase + rowR) * 512;

    float sacc = 0.f, qacc = 0.f;                // LN stats, fixed row per thread
    f32x4 acc0 = (f32x4)0.f;
    f32x4 acc1 = (f32x4)0.f;

    // convert two float4 (by value) into buf; verbatim R8 order
    auto convert = [&](float4 v0_, float4 v1_, int buf) {
        #pragma unroll
        for (int j = 0; j < 2; ++j) {
            float4 v = j ? v1_ : v0_;
            sacc += v.x + v.y + v.z + v.w;
            qacc += v.x * v.x + v.y * v.y + v.z * v.z + v.w * v.w;
            _Float16 h0 = (_Float16)v.x, h1 = (_Float16)v.y,
                     h2 = (_Float16)v.z, h3 = (_Float16)v.w;
            _Float16 l0 = (_Float16)((v.x - (float)h0) * 2048.f);
            _Float16 l1 = (_Float16)((v.y - (float)h1) * 2048.f);
            _Float16 l2 = (_Float16)((v.z - (float)h2) * 2048.f);
            _Float16 l3 = (_Float16)((v.w - (float)h3) * 2048.f);
            half4h hh = {h0, h1, h2, h3};
            half4h ll = {l0, l1, l2, l3};
            int col = (cS + j * 16) * 4;
            *(half4h*)&Xh[buf][rowR][col] = hh;
            *(half4h*)&Xl[buf][rowR][col] = ll;
        }
    };
    // iteration-scoped W load + MFMA for one chunk (verbatim R3/R8 order)
    auto loadW = [&](half8* Wh, half8* Wl, int c) {
        #pragma unroll
        for (int ks = 0; ks < 4; ++ks) {
            int bo = (((c * 4 + ks) * 4 + et) * 64 + lane) * 8;
            Wh[ks] = *(const half8*)&Bh[bo];
            Wl[ks] = *(const half8*)&Bl[bo];
        }
    };
    auto mfmaC = [&](const half8* Wh, const half8* Wl, int buf) {
        #pragma unroll
        for (int ks = 0; ks < 4; ++ks) {
            half8 Ah = *(const half8*)&Xh[buf][arow][ks * 32 + q * 8];
            half8 Al = *(const half8*)&Xl[buf][arow][ks * 32 + q * 8];
            acc0 = MFMA16(Ah, Wh[ks], acc0);
            acc1 = MFMA16(Ah, Wl[ks], acc1);
            acc1 = MFMA16(Al, Wh[ks], acc1);
        }
    };

    // loop-carried X prefetch: 2 chunks deep, individually named
    float4 vA0, vA1, vB0, vB1;

    // prologue: X(0) load+convert into buf0, X(1) -> vA pair
    {
        float4 v00 = Xrow[cS];
        float4 v01 = Xrow[cS + 16];
        vA0 = Xrow[32 + cS];
        vA1 = Xrow[32 + cS + 16];
        convert(v00, v01, 0);
    }
    __syncthreads();

    for (int c = 0; c < NCH; c += 2) {
        // ---- even chunk c: MFMA buf0; vA holds X(c+1); issue X(c+2)->vB ----
        {
            half8 Wh[4], Wl[4];
            loadW(Wh, Wl, c);
            if (c + 2 < NCH) {
                vB0 = Xrow[(c + 2) * 32 + cS];
                vB1 = Xrow[(c + 2) * 32 + cS + 16];
            }
            mfmaC(Wh, Wl, 0);
            convert(vA0, vA1, 1);
        }
        __syncthreads();

        // ---- odd chunk c+1: MFMA buf1; vB holds X(c+2); issue X(c+3)->vA ----
        {
            half8 Wh[4], Wl[4];
            loadW(Wh, Wl, c + 1);
            if (c + 3 < NCH) {
                vA0 = Xrow[(c + 3) * 32 + cS];
                vA1 = Xrow[(c + 3) * 32 + cS + 16];
            }
            mfmaC(Wh, Wl, 1);
            if (c + 2 < NCH) convert(vB0, vB1, 0);
        }
        __syncthreads();
    }

    // ---- finalize LN stats (16 lanes per row: bits 0-3 of lane) ----
    {
        float s = sacc, qq = qacc;
        #pragma unroll
        for (int d = 1; d < 16; d <<= 1) {
            s  += __shfl_xor(s, d);
            qq += __shfl_xor(qq, d);
        }
        if (cS == 0) {
            float mu  = s * (1.f / H);
            float var = qq * (1.f / H) - mu * mu;
            mu_s[rowR] = mu;
            rs_s[rowR] = rsqrtf(var + 1e-5f);
        }
    }
    __syncthreads();

    // ---- epilogue: combine splits, LN rank-1 correction, clip, write logits ----
    {
        int n = et * 16 + ln16;
        float cs = csum[n], bs = bsum[n];
        #pragma unroll
        for (int reg = 0; reg < 4; ++reg) {
            int r = mt * 16 + q * 4 + reg;
            float raw = acc0[reg] + acc1[reg] * (1.f / 2048.f);
            float lg = rs_s[r] * (raw - mu_s[r] * cs) + bs;
            lg = fminf(fmaxf(lg, -10.f), 10.f);
            out[lOff + (rowBase + r) * 64 + n] = lg;
            C2[r][n] = lg;
        }
    }
    __syncthreads();

    // ---- softmax + top2: wave w handles rows w*4 .. w*4+3 ----
    #pragma unroll
    for (int rr = 0; rr < 4; ++rr) {
        int r = w * 4 + rr;
        float l = C2[r][lane];
        float m = l;
        #pragma unroll
        for (int d = 1; d < 64; d <<= 1) m = fmaxf(m, __shfl_xor(m, d));
        float p = __expf(l - m);
        float ssum = p;
        #pragma unroll
        for (int d = 1; d < 64; d <<= 1) ssum += __shfl_xor(ssum, d);
        float prob = fminf(fmaxf(p / ssum, 1e-4f), 1.0f);

        float v1 = prob; int i1 = lane;
        #pragma unroll
        for (int d = 1; d < 64; d <<= 1) {
            float ov = __shfl_xor(v1, d);
            int   oi = __shfl_xor(i1, d);
            if (ov > v1 || (ov == v1 && oi < i1)) { v1 = ov; i1 = oi; }
        }
        float v2 = (lane == i1) ? -1.f : prob; int i2 = lane;
        #pragma unroll
        for (int d = 1; d < 64; d <<= 1) {
            float ov = __shfl_xor(v2, d);
            int   oi = __shfl_xor(i2, d);
            if (ov > v2 || (ov == v2 && oi < i2)) { v2 = ov; i2 = oi; }
        }
        if (lane == 0) {
            float ps = fmaxf(v1 + v2, 1e-4f);
            long rg_ = rowBase + r;
            out[rg_ * 2 + 0] = v1 / ps;
            out[rg_ * 2 + 1] = v2 / ps;
            out[iOff + rg_ * 2 + 0] = (float)i1;
            out[iOff + rg_ * 2 + 1] = (float)i2;
        }
    }
}

extern "C" void kernel_launch(void* const* d_in, const int* in_sizes, int n_in,
                              void* d_out, int out_size, void* d_ws, size_t ws_size,
                              hipStream_t stream) {
    const float* X   = (const float*)d_in[0];
    const float* lnw = (const float*)d_in[1];
    const float* lnb = (const float*)d_in[2];
    const float* W   = (const float*)d_in[3];
    float* outp = (float*)d_out;

    _Float16* Bh = (_Float16*)d_ws;
    _Float16* Bl = Bh + H * E;
    float* csum  = (float*)(Bl + H * E);
    float* bsum  = csum + E;

    int N = in_sizes[0] / H;                 // 16384 rows

    prep_fused<<<64, 256, 0, stream>>>(W, lnw, lnb, Bh, Bl, csum, bsum);
    router_kernel<<<N / MR, 512, 0, stream>>>(X, Bh, Bl, csum, bsum, outp, N);
}

// Round 12
// 210.082 us; speedup vs baseline: 1.3754x; 1.0425x over previous
//
#include <hip/hip_runtime.h>
#include <math.h>

#define H 2048
#define E 64
#define MR 16        // rows per block
#define NCH 8        // 256-wide k chunks (was 16x128: same k order, half the barriers)
#define LR 264       // LDS row stride in f16 (256 + 8 pad; 528 B rows, 16B-aligned)

typedef _Float16 half8  __attribute__((ext_vector_type(8)));
typedef _Float16 half4h __attribute__((ext_vector_type(4)));
typedef float    f32x4  __attribute__((ext_vector_type(4)));

#define MFMA16(A,B,C) __builtin_amdgcn_mfma_f32_16x16x32_f16(A,B,C,0,0,0)

// ws layout: Bh[H*E f16] | Bl[H*E f16] | csum[E f32] | bsum[E f32]

// Fused prep: pack W' = lnw*W into MFMA B-fragment layout (hi/lo f16 planes,
// lo scaled by 2048)  +  per-expert csum/bsum reductions. Grid = 64.
// Verified numerics-neutral in R6-R11.
__global__ __launch_bounds__(256) void prep_fused(const float* __restrict__ W,
        const float* __restrict__ lnw, const float* __restrict__ lnb,
        _Float16* __restrict__ Bh, _Float16* __restrict__ Bl,
        float* __restrict__ csum, float* __restrict__ bsum) {
    // ---- pack part ----
    {
        int idx  = blockIdx.x * 256 + threadIdx.x;      // 0..16383
        int lane = idx & 63;
        int e  = ((idx >> 6) & 3) * 16 + (lane & 15);
        int k0 = (idx >> 8) * 32 + ((lane >> 4) << 3);
        half8 hh, ll;
        #pragma unroll
        for (int j = 0; j < 8; ++j) {
            float wf = lnw[k0 + j] * W[e * H + k0 + j];
            _Float16 h = (_Float16)wf;
            _Float16 l = (_Float16)((wf - (float)h) * 2048.0f);
            hh[j] = h; ll[j] = l;
        }
        *(half8*)&Bh[(long)idx * 8] = hh;
        *(half8*)&Bl[(long)idx * 8] = ll;
    }
    // ---- sums part (expert = blockIdx.x) ----
    {
        __shared__ float rc[256], rb[256];
        int e = blockIdx.x, t = threadIdx.x;
        float cs = 0.f, bs = 0.f;
        #pragma unroll
        for (int j = 0; j < 8; ++j) {
            int k = t + j * 256;
            float w = W[e * H + k];
            cs += lnw[k] * w;
            bs += lnb[k] * w;
        }
        rc[t] = cs; rb[t] = bs;
        __syncthreads();
        for (int s = 128; s > 0; s >>= 1) {
            if (t < s) { rc[t] += rc[t + s]; rb[t] += rb[t + s]; }
            __syncthreads();
        }
        if (t == 0) { csum[e] = rc[0]; bsum[e] = rb[0]; }
    }
}

// R8 champion with KCH=256 (8 phases instead of 16). Per-thread k order for
// both the MFMA accumulation (ks 0..7 sequential) and the convert/stats
// (cS, cS+16, cS+32, cS+48 per chunk == old chunks 2c,2c+1 concatenated) is
// BIT-IDENTICAL to R8 -- only barrier positions change. W is loaded per
// HALF-chunk (two iteration-scoped 32-VGPR bursts) to avoid the R6 spill.
__global__ __launch_bounds__(256, 4) void router_kernel(
    const float* __restrict__ X, const _Float16* __restrict__ Bh,
    const _Float16* __restrict__ Bl, const float* __restrict__ csum,
    const float* __restrict__ bsum, float* __restrict__ out, int nRows)
{
    __shared__ __align__(16) _Float16 Xh[2][MR][LR];   // 16,896 B
    __shared__ __align__(16) _Float16 Xl[2][MR][LR];   // 16,896 B
    __shared__ float C2[MR][E + 4];                    //  4,352 B
    __shared__ float mu_s[MR], rs_s[MR];
    // ~38.3 KB LDS -> 4 blocks/CU resident (160/38.3), 16 waves/CU

    const int t    = threadIdx.x;
    const int lane = t & 63;
    const int et   = t >> 6;                 // wave -> expert tile (16 experts)
    const int q    = lane >> 4;
    const int ln16 = lane & 15;
    const int rowR = t >> 4;                 // staging/stats row 0..15 (16 thr/row)
    const int cS   = t & 15;                 // float4 col group within chunk
    const long rowBase = (long)blockIdx.x * MR;
    const long iOff = (long)nRows * 2;
    const long lOff = (long)nRows * 4;

    const float4* Xrow = (const float4*)X + (rowBase + rowR) * 512;

    float sacc = 0.f, qacc = 0.f;            // LN stats, fixed row per thread
    f32x4 acc0 = (f32x4)0.f;
    f32x4 acc1 = (f32x4)0.f;

    // convert four float4 (by value) into buf; same per-thread k order as R8
    auto convert = [&](float4 w0, float4 w1, float4 w2, float4 w3, int buf) {
        #pragma unroll
        for (int j = 0; j < 4; ++j) {
            float4 v = (j == 0) ? w0 : (j == 1) ? w1 : (j == 2) ? w2 : w3;
            sacc += v.x + v.y + v.z + v.w;
            qacc += v.x * v.x + v.y * v.y + v.z * v.z + v.w * v.w;
            _Float16 h0 = (_Float16)v.x, h1 = (_Float16)v.y,
                     h2 = (_Float16)v.z, h3 = (_Float16)v.w;
            _Float16 l0 = (_Float16)((v.x - (float)h0) * 2048.f);
            _Float16 l1 = (_Float16)((v.y - (float)h1) * 2048.f);
            _Float16 l2 = (_Float16)((v.z - (float)h2) * 2048.f);
            _Float16 l3 = (_Float16)((v.w - (float)h3) * 2048.f);
            half4h hh = {h0, h1, h2, h3};
            half4h ll = {l0, l1, l2, l3};
            int col = (cS + j * 16) * 4;
            *(half4h*)&Xh[buf][rowR][col] = hh;
            *(half4h*)&Xl[buf][rowR][col] = ll;
        }
    };
    // iteration-scoped W load for one HALF-chunk (4 x 32-wide k steps)
    auto loadW4 = [&](half8* Wh, half8* Wl, int c, int h) {
        #pragma unroll
        for (int ks = 0; ks < 4; ++ks) {
            int gks = c * 8 + h * 4 + ks;
            int bo = ((gks * 4 + et) * 64 + lane) * 8;
            Wh[ks] = *(const half8*)&Bh[bo];
            Wl[ks] = *(const half8*)&Bl[bo];
        }
    };
    auto mfma4 = [&](const half8* Wh, const half8* Wl, int buf, int h) {
        #pragma unroll
        for (int ks = 0; ks < 4; ++ks) {
            int col = (h * 4 + ks) * 32 + q * 8;
            half8 Ah = *(const half8*)&Xh[buf][ln16][col];
            half8 Al = *(const half8*)&Xl[buf][ln16][col];
            acc0 = MFMA16(Ah, Wh[ks], acc0);
            acc1 = MFMA16(Ah, Wl[ks], acc1);
            acc1 = MFMA16(Al, Wh[ks], acc1);
        }
    };
    // one full chunk: two W half-bursts, X prefetch issued between halves
    auto chunkPhase = [&](int c, int buf, bool pf, float4& p0, float4& p1,
                          float4& p2, float4& p3) {
        half8 Wh[4], Wl[4];
        loadW4(Wh, Wl, c, 0);
        if (pf) {
            p0 = Xrow[(c + 2) * 64 + cS];
            p1 = Xrow[(c + 2) * 64 + cS + 16];
            p2 = Xrow[(c + 2) * 64 + cS + 32];
            p3 = Xrow[(c + 2) * 64 + cS + 48];
        }
        mfma4(Wh, Wl, buf, 0);
        loadW4(Wh, Wl, c, 1);
        mfma4(Wh, Wl, buf, 1);
    };

    // loop-carried X prefetch: 2 chunks deep, individually named
    float4 vA0, vA1, vA2, vA3, vB0, vB1, vB2, vB3;

    // prologue: X(0) load+convert into buf0, X(1) -> vA quad
    {
        float4 u0 = Xrow[cS];
        float4 u1 = Xrow[cS + 16];
        float4 u2 = Xrow[cS + 32];
        float4 u3 = Xrow[cS + 48];
        vA0 = Xrow[64 + cS];
        vA1 = Xrow[64 + cS + 16];
        vA2 = Xrow[64 + cS + 32];
        vA3 = Xrow[64 + cS + 48];
        convert(u0, u1, u2, u3, 0);
    }
    __syncthreads();

    for (int c = 0; c < NCH; c += 2) {
        // ---- even chunk c: MFMA buf0; vA holds X(c+1); issue X(c+2)->vB ----
        chunkPhase(c, 0, c + 2 < NCH, vB0, vB1, vB2, vB3);
        convert(vA0, vA1, vA2, vA3, 1);
        __syncthreads();

        // ---- odd chunk c+1: MFMA buf1; vB holds X(c+2); issue X(c+3)->vA ----
        chunkPhase(c + 1, 1, c + 3 < NCH, vA0, vA1, vA2, vA3);
        if (c + 2 < NCH) convert(vB0, vB1, vB2, vB3, 0);
        __syncthreads();
    }

    // ---- finalize LN stats (16 lanes per row: bits 0-3 of lane) ----
    {
        float s = sacc, qq = qacc;
        #pragma unroll
        for (int d = 1; d < 16; d <<= 1) {
            s  += __shfl_xor(s, d);
            qq += __shfl_xor(qq, d);
        }
        if (cS == 0) {
            float mu  = s * (1.f / H);
            float var = qq * (1.f / H) - mu * mu;
            mu_s[rowR] = mu;
            rs_s[rowR] = rsqrtf(var + 1e-5f);
        }
    }
    __syncthreads();

    // ---- epilogue: combine splits, LN rank-1 correction, clip, write logits ----
    {
        int n = et * 16 + ln16;
        float cs = csum[n], bs = bsum[n];
        #pragma unroll
        for (int reg = 0; reg < 4; ++reg) {
            int r = q * 4 + reg;
            float raw = acc0[reg] + acc1[reg] * (1.f / 2048.f);
            float lg = rs_s[r] * (raw - mu_s[r] * cs) + bs;
            lg = fminf(fmaxf(lg, -10.f), 10.f);
            out[lOff + (rowBase + r) * 64 + n] = lg;
            C2[r][n] = lg;
        }
    }
    __syncthreads();

    // ---- softmax + top2: wave et handles rows et*4 .. et*4+3 ----
    #pragma unroll
    for (int rr = 0; rr < 4; ++rr) {
        int r = et * 4 + rr;
        float l = C2[r][lane];
        float m = l;
        #pragma unroll
        for (int d = 1; d < 64; d <<= 1) m = fmaxf(m, __shfl_xor(m, d));
        float p = __expf(l - m);
        float ssum = p;
        #pragma unroll
        for (int d = 1; d < 64; d <<= 1) ssum += __shfl_xor(ssum, d);
        float prob = fminf(fmaxf(p / ssum, 1e-4f), 1.0f);

        float v1 = prob; int i1 = lane;
        #pragma unroll
        for (int d = 1; d < 64; d <<= 1) {
            float ov = __shfl_xor(v1, d);
            int   oi = __shfl_xor(i1, d);
            if (ov > v1 || (ov == v1 && oi < i1)) { v1 = ov; i1 = oi; }
        }
        float v2 = (lane == i1) ? -1.f : prob; int i2 = lane;
        #pragma unroll
        for (int d = 1; d < 64; d <<= 1) {
            float ov = __shfl_xor(v2, d);
            int   oi = __shfl_xor(i2, d);
            if (ov > v2 || (ov == v2 && oi < i2)) { v2 = ov; i2 = oi; }
        }
        if (lane == 0) {
            float ps = fmaxf(v1 + v2, 1e-4f);
            long rg_ = rowBase + r;
            out[rg_ * 2 + 0] = v1 / ps;
            out[rg_ * 2 + 1] = v2 / ps;
            out[iOff + rg_ * 2 + 0] = (float)i1;
            out[iOff + rg_ * 2 + 1] = (float)i2;
        }
    }
}

extern "C" void kernel_launch(void* const* d_in, const int* in_sizes, int n_in,
                              void* d_out, int out_size, void* d_ws, size_t ws_size,
                              hipStream_t stream) {
    const float* X   = (const float*)d_in[0];
    const float* lnw = (const float*)d_in[1];
    const float* lnb = (const float*)d_in[2];
    const float* W   = (const float*)d_in[3];
    float* outp = (float*)d_out;

    _Float16* Bh = (_Float16*)d_ws;
    _Float16* Bl = Bh + H * E;
    float* csum  = (float*)(Bl + H * E);
    float* bsum  = csum + E;

    int N = in_sizes[0] / H;                 // 16384 rows

    prep_fused<<<64, 256, 0, stream>>>(W, lnw, lnb, Bh, Bl, csum, bsum);
    router_kernel<<<N / MR, 256, 0, stream>>>(X, Bh, Bl, csum, bsum, outp, N);
}